// Round 1
// baseline (1109.736 us; speedup 1.0000x reference)
//
#include <hip/hip_runtime.h>
#include <hip/hip_bf16.h>

#define NSPH 7

typedef short bf16x8 __attribute__((ext_vector_type(8)));
typedef float f32x4 __attribute__((ext_vector_type(4)));

static __device__ __forceinline__ ushort f2b(float f) {
    union { __hip_bfloat16 h; ushort u; } v; v.h = __float2bfloat16(f); return v.u;
}
static __device__ __forceinline__ float b2f(ushort u) {
    union { unsigned int i; float f; } v; v.i = ((unsigned int)u) << 16; return v.f;
}
static __device__ __forceinline__ float silu_f(float v) {
    return v / (1.0f + __expf(-v));
}
// load 8 consecutive f32 from p, round to bf16x8
static __device__ __forceinline__ bf16x8 ld8_f32_to_bf16(const float* p) {
    float4 p0 = *(const float4*)p;
    float4 p1 = *(const float4*)(p + 4);
    bf16x8 r;
    r[0] = (short)f2b(p0.x); r[1] = (short)f2b(p0.y);
    r[2] = (short)f2b(p0.z); r[3] = (short)f2b(p0.w);
    r[4] = (short)f2b(p1.x); r[5] = (short)f2b(p1.y);
    r[6] = (short)f2b(p1.z); r[7] = (short)f2b(p1.w);
    return r;
}

// ---------------------------------------------------------------------------
// K1: X[E,64] = silu(edge[E,128] @ W_down[64,128]^T), X stored bf16.
// ---------------------------------------------------------------------------
__launch_bounds__(256)
__global__ void k1_down(const float* __restrict__ edge, const float* __restrict__ Wd,
                        ushort* __restrict__ X) {
    const int tid  = threadIdx.x;
    const int lane = tid & 63;
    const int w    = tid >> 6;
    const int quad = lane >> 4;
    const int m16  = lane & 15;
    const int r0   = blockIdx.x * 128 + w * 32;

    f32x4 acc[2][4];
#pragma unroll
    for (int mi = 0; mi < 2; mi++)
#pragma unroll
        for (int ni = 0; ni < 4; ni++) acc[mi][ni] = (f32x4){0.f, 0.f, 0.f, 0.f};

#pragma unroll
    for (int k = 0; k < 128; k += 32) {
        bf16x8 a[2], b[4];
#pragma unroll
        for (int mi = 0; mi < 2; mi++)
            a[mi] = ld8_f32_to_bf16(&edge[(size_t)(r0 + mi * 16 + m16) * 128 + k + quad * 8]);
#pragma unroll
        for (int ni = 0; ni < 4; ni++)
            b[ni] = ld8_f32_to_bf16(&Wd[(ni * 16 + m16) * 128 + k + quad * 8]);
#pragma unroll
        for (int mi = 0; mi < 2; mi++)
#pragma unroll
            for (int ni = 0; ni < 4; ni++)
                acc[mi][ni] = __builtin_amdgcn_mfma_f32_16x16x32_bf16(a[mi], b[ni], acc[mi][ni], 0, 0, 0);
    }
#pragma unroll
    for (int mi = 0; mi < 2; mi++)
#pragma unroll
        for (int ni = 0; ni < 4; ni++)
#pragma unroll
            for (int r = 0; r < 4; r++) {
                int row = r0 + mi * 16 + quad * 4 + r;
                int col = ni * 16 + m16;
                X[(size_t)row * 64 + col] = f2b(silu_f(acc[mi][ni][r]));
            }
}

// ---------------------------------------------------------------------------
// Counting-sort of triplets by idx_ji:
//   k_hist:       counts[ji[t]]++
//   k_scan_bsum:  per-256-chunk sums
//   k_scan_top:   exclusive scan of chunk sums (single block)
//   k_scan_down:  offsets[] = global exclusive scan of counts
//   k_scatter_idx: perm[atomicAdd(offsets[ji[t]],1)] = t   (offsets -> ends)
// ---------------------------------------------------------------------------
__launch_bounds__(256)
__global__ void k_hist(const int* __restrict__ ji, int* __restrict__ counts, int T) {
    int i = blockIdx.x * 256 + threadIdx.x;
    int n = gridDim.x * 256;
    for (int t = i; t < T; t += n) atomicAdd(&counts[ji[t]], 1);
}

__launch_bounds__(256)
__global__ void k_scan_bsum(const int* __restrict__ counts, int* __restrict__ bsum) {
    __shared__ int sm[256];
    int tid = threadIdx.x;
    sm[tid] = counts[blockIdx.x * 256 + tid];
    __syncthreads();
#pragma unroll
    for (int off = 128; off > 0; off >>= 1) {
        if (tid < off) sm[tid] += sm[tid + off];
        __syncthreads();
    }
    if (tid == 0) bsum[blockIdx.x] = sm[0];
}

__launch_bounds__(1024)
__global__ void k_scan_top(int* __restrict__ bsum, int NB) {
    __shared__ int sm[1024];
    int tid = threadIdx.x;
    int v = (tid < NB) ? bsum[tid] : 0;
    sm[tid] = v;
    __syncthreads();
    for (int off = 1; off < 1024; off <<= 1) {
        int x = (tid >= off) ? sm[tid - off] : 0;
        __syncthreads();
        sm[tid] += x;
        __syncthreads();
    }
    if (tid < NB) bsum[tid] = sm[tid] - v;  // exclusive
}

__launch_bounds__(256)
__global__ void k_scan_down(const int* __restrict__ counts, const int* __restrict__ bsum,
                            int* __restrict__ offsets) {
    __shared__ int sm[256];
    int tid = threadIdx.x;
    int g = blockIdx.x * 256 + tid;
    int v = counts[g];
    sm[tid] = v;
    __syncthreads();
    for (int off = 1; off < 256; off <<= 1) {
        int x = (tid >= off) ? sm[tid - off] : 0;
        __syncthreads();
        sm[tid] += x;
        __syncthreads();
    }
    offsets[g] = bsum[blockIdx.x] + sm[tid] - v;
}

__launch_bounds__(256)
__global__ void k_scatter_idx(const int* __restrict__ ji, int* __restrict__ cursor,
                              int* __restrict__ perm, int T) {
    int i = blockIdx.x * 256 + threadIdx.x;
    int n = gridDim.x * 256;
    for (int t = i; t < T; t += n) {
        int pos = atomicAdd(&cursor[ji[t]], 1);
        perm[pos] = t;
    }
}

// ---------------------------------------------------------------------------
// K2': one wave per segment r (grid-stride). Walks its private triplet list,
// accumulates in registers, ONE plain store per segment. No atomics.
// lane = output column (0..63). t, kj[t], sbf[t,:] are wave-uniform (scalar).
// agg[r] lives interleaved in out rows: out[r*128 + 0..63].
// ---------------------------------------------------------------------------
__launch_bounds__(256)
__global__ void k2_seg(const int* __restrict__ kj, const int* __restrict__ perm,
                       const int* __restrict__ counts, const int* __restrict__ ends,
                       const float* __restrict__ sbf, const ushort* __restrict__ X,
                       const float* __restrict__ Wsbf, const float* __restrict__ Wsbf0,
                       float* __restrict__ out, int E) {
    const int lane = threadIdx.x & 63;
    // wc[lane][k] = (W_sbf @ W_sbf0)[lane][k], computed once per thread
    float wj[NSPH], wc[NSPH];
#pragma unroll
    for (int i = 0; i < NSPH; i++) wj[i] = Wsbf[lane * NSPH + i];
#pragma unroll
    for (int k = 0; k < NSPH; k++) {
        float a = 0.f;
#pragma unroll
        for (int i = 0; i < NSPH; i++) a += wj[i] * Wsbf0[i * NSPH + k];
        wc[k] = a;
    }
    int gw = (blockIdx.x * 256 + threadIdx.x) >> 6;
    int nw = (gridDim.x * 256) >> 6;
    for (int r = gw; r < E; r += nw) {
        int rs  = __builtin_amdgcn_readfirstlane(r);
        int c   = counts[rs];
        int end = ends[rs];      // after scatter, offsets[] holds segment ends
        int st  = end - c;
        float acc = 0.f;
        for (int i = 0; i < c; i++) {
            int t = __builtin_amdgcn_readfirstlane(perm[st + i]);
            int a = kj[t];
            float s = 0.f;
#pragma unroll
            for (int k = 0; k < NSPH; k++) s += wc[k] * sbf[(size_t)t * NSPH + k];
            acc += b2f(X[(size_t)a * 64 + lane]) * s;
        }
        out[(size_t)rs * 128 + lane] = acc;  // zero for empty segments
    }
}

// ---------------------------------------------------------------------------
// K3 (fused), per 128-row block:
//   GEMM1: Utile[128,128] = silu(agg_tile[128,64] @ W_up[128,64]^T) -> LDS bf16
//   GEMM2: out = silu([edge_tile | Utile] @ W_e1[128,256]^T + b) + edge_tile
// ---------------------------------------------------------------------------
__launch_bounds__(256)
__global__ void k3_fused(const float* __restrict__ edge, const float* __restrict__ Wu,
                         const float* __restrict__ We, const float* __restrict__ bias,
                         float* out) {
    __shared__ __align__(16) short Ut[128 * 136];
    const int tid  = threadIdx.x;
    const int lane = tid & 63;
    const int w    = tid >> 6;
    const int quad = lane >> 4;
    const int m16  = lane & 15;
    const int r0   = blockIdx.x * 128;
    const int rowbase = (w >> 1) * 64;
    const int colbase = (w & 1) * 64;

    // ---- GEMM1 ----
    f32x4 acc1[4][4];
#pragma unroll
    for (int mi = 0; mi < 4; mi++)
#pragma unroll
        for (int ni = 0; ni < 4; ni++) acc1[mi][ni] = (f32x4){0.f, 0.f, 0.f, 0.f};

#pragma unroll
    for (int kk = 0; kk < 64; kk += 32) {
        bf16x8 a[4], b[4];
#pragma unroll
        for (int mi = 0; mi < 4; mi++)
            a[mi] = ld8_f32_to_bf16(&out[(size_t)(r0 + rowbase + mi * 16 + m16) * 128 + kk + quad * 8]);
#pragma unroll
        for (int ni = 0; ni < 4; ni++)
            b[ni] = ld8_f32_to_bf16(&Wu[(colbase + ni * 16 + m16) * 64 + kk + quad * 8]);
#pragma unroll
        for (int mi = 0; mi < 4; mi++)
#pragma unroll
            for (int ni = 0; ni < 4; ni++)
                acc1[mi][ni] = __builtin_amdgcn_mfma_f32_16x16x32_bf16(a[mi], b[ni], acc1[mi][ni], 0, 0, 0);
    }
#pragma unroll
    for (int mi = 0; mi < 4; mi++)
#pragma unroll
        for (int ni = 0; ni < 4; ni++)
#pragma unroll
            for (int r = 0; r < 4; r++) {
                int rl = rowbase + mi * 16 + quad * 4 + r;
                int cl = colbase + ni * 16 + m16;
                Ut[rl * 136 + cl] = (short)f2b(silu_f(acc1[mi][ni][r]));
            }
    __syncthreads();

    // ---- GEMM2 ----
    f32x4 acc2[4][4];
#pragma unroll
    for (int mi = 0; mi < 4; mi++)
#pragma unroll
        for (int ni = 0; ni < 4; ni++) acc2[mi][ni] = (f32x4){0.f, 0.f, 0.f, 0.f};

#pragma unroll
    for (int k = 0; k < 256; k += 32) {
        bf16x8 a[4], b[4];
#pragma unroll
        for (int mi = 0; mi < 4; mi++) {
            int rl = rowbase + mi * 16 + m16;
            if (k < 128)
                a[mi] = ld8_f32_to_bf16(&edge[(size_t)(r0 + rl) * 128 + k + quad * 8]);
            else
                a[mi] = *(const bf16x8*)&Ut[rl * 136 + (k - 128) + quad * 8];
        }
#pragma unroll
        for (int ni = 0; ni < 4; ni++)
            b[ni] = ld8_f32_to_bf16(&We[(size_t)(colbase + ni * 16 + m16) * 256 + k + quad * 8]);
#pragma unroll
        for (int mi = 0; mi < 4; mi++)
#pragma unroll
            for (int ni = 0; ni < 4; ni++)
                acc2[mi][ni] = __builtin_amdgcn_mfma_f32_16x16x32_bf16(a[mi], b[ni], acc2[mi][ni], 0, 0, 0);
    }

#pragma unroll
    for (int mi = 0; mi < 4; mi++)
#pragma unroll
        for (int ni = 0; ni < 4; ni++) {
            int col = colbase + ni * 16 + m16;
            float bcol = bias[col];
#pragma unroll
            for (int r = 0; r < 4; r++) {
                int row = r0 + rowbase + mi * 16 + quad * 4 + r;
                float pre = acc2[mi][ni][r] + bcol;
                out[(size_t)row * 128 + col] = silu_f(pre) + edge[(size_t)row * 128 + col];
            }
        }
}

// ---------------------------------------------------------------------------
extern "C" void kernel_launch(void* const* d_in, const int* in_sizes, int n_in,
                              void* d_out, int out_size, void* d_ws, size_t ws_size,
                              hipStream_t stream) {
    const float* edge  = (const float*)d_in[0];
    const float* sbf   = (const float*)d_in[1];
    const int*   idxkj = (const int*)d_in[2];
    const int*   idxji = (const int*)d_in[3];
    const float* Wsbf0 = (const float*)d_in[4];
    const float* Wsbf  = (const float*)d_in[5];
    const float* We1   = (const float*)d_in[6];
    const float* be1   = (const float*)d_in[7];
    const float* Wdown = (const float*)d_in[8];
    const float* Wup   = (const float*)d_in[9];

    const int E = in_sizes[0] / 128;
    const int T = in_sizes[2];
    const int NB = E / 256;  // 1024 for E=262144

    // workspace layout: X | counts | offsets | perm | blocksums  (~44 MB)
    ushort* X       = (ushort*)d_ws;                                  // E*64 bf16
    int*    counts  = (int*)((char*)d_ws + (size_t)E * 64 * 2);       // E
    int*    offsets = counts + E;                                     // E
    int*    perm    = offsets + E;                                    // T
    int*    bsum    = perm + T;                                       // NB (<=1024)

    float* out = (float*)d_out;  // E*128 f32; agg aliased at out[r*128 + 0..63]

    hipMemsetAsync(counts, 0, (size_t)E * sizeof(int), stream);

    k1_down<<<E / 128, 256, 0, stream>>>(edge, Wdown, X);

    // counting sort of triplets by ji
    k_hist<<<2048, 256, 0, stream>>>(idxji, counts, T);
    k_scan_bsum<<<NB, 256, 0, stream>>>(counts, bsum);
    k_scan_top<<<1, 1024, 0, stream>>>(bsum, NB);
    k_scan_down<<<NB, 256, 0, stream>>>(counts, bsum, offsets);
    k_scatter_idx<<<2048, 256, 0, stream>>>(idxji, offsets, perm, T);

    // ownership-based segment reduction (no atomics, no memset of out)
    k2_seg<<<4096, 256, 0, stream>>>(idxkj, perm, counts, offsets, sbf, X,
                                     Wsbf, Wsbf0, out, E);

    k3_fused<<<E / 128, 256, 0, stream>>>(edge, Wup, We1, be1, out);
}

// Round 2
// 874.272 us; speedup vs baseline: 1.2693x; 1.2693x over previous
//
#include <hip/hip_runtime.h>
#include <hip/hip_bf16.h>

#define NSPH 7

typedef short bf16x8 __attribute__((ext_vector_type(8)));
typedef float f32x4 __attribute__((ext_vector_type(4)));

static __device__ __forceinline__ ushort f2b(float f) {
    union { __hip_bfloat16 h; ushort u; } v; v.h = __float2bfloat16(f); return v.u;
}
static __device__ __forceinline__ float b2f(ushort u) {
    union { unsigned int i; float f; } v; v.i = ((unsigned int)u) << 16; return v.f;
}
static __device__ __forceinline__ float silu_f(float v) {
    return v / (1.0f + __expf(-v));
}
// load 8 consecutive f32 from p, round to bf16x8
static __device__ __forceinline__ bf16x8 ld8_f32_to_bf16(const float* p) {
    float4 p0 = *(const float4*)p;
    float4 p1 = *(const float4*)(p + 4);
    bf16x8 r;
    r[0] = (short)f2b(p0.x); r[1] = (short)f2b(p0.y);
    r[2] = (short)f2b(p0.z); r[3] = (short)f2b(p0.w);
    r[4] = (short)f2b(p1.x); r[5] = (short)f2b(p1.y);
    r[6] = (short)f2b(p1.z); r[7] = (short)f2b(p1.w);
    return r;
}

// ---------------------------------------------------------------------------
// K1: X[E,64] = silu(edge[E,128] @ W_down[64,128]^T), X stored bf16.
// ---------------------------------------------------------------------------
__launch_bounds__(256)
__global__ void k1_down(const float* __restrict__ edge, const float* __restrict__ Wd,
                        ushort* __restrict__ X) {
    const int tid  = threadIdx.x;
    const int lane = tid & 63;
    const int w    = tid >> 6;
    const int quad = lane >> 4;
    const int m16  = lane & 15;
    const int r0   = blockIdx.x * 128 + w * 32;

    f32x4 acc[2][4];
#pragma unroll
    for (int mi = 0; mi < 2; mi++)
#pragma unroll
        for (int ni = 0; ni < 4; ni++) acc[mi][ni] = (f32x4){0.f, 0.f, 0.f, 0.f};

#pragma unroll
    for (int k = 0; k < 128; k += 32) {
        bf16x8 a[2], b[4];
#pragma unroll
        for (int mi = 0; mi < 2; mi++)
            a[mi] = ld8_f32_to_bf16(&edge[(size_t)(r0 + mi * 16 + m16) * 128 + k + quad * 8]);
#pragma unroll
        for (int ni = 0; ni < 4; ni++)
            b[ni] = ld8_f32_to_bf16(&Wd[(ni * 16 + m16) * 128 + k + quad * 8]);
#pragma unroll
        for (int mi = 0; mi < 2; mi++)
#pragma unroll
            for (int ni = 0; ni < 4; ni++)
                acc[mi][ni] = __builtin_amdgcn_mfma_f32_16x16x32_bf16(a[mi], b[ni], acc[mi][ni], 0, 0, 0);
    }
#pragma unroll
    for (int mi = 0; mi < 2; mi++)
#pragma unroll
        for (int ni = 0; ni < 4; ni++)
#pragma unroll
            for (int r = 0; r < 4; r++) {
                int row = r0 + mi * 16 + quad * 4 + r;
                int col = ni * 16 + m16;
                X[(size_t)row * 64 + col] = f2b(silu_f(acc[mi][ni][r]));
            }
}

// ---------------------------------------------------------------------------
// Counting-sort of triplets by idx_ji (payload sort — no perm array):
//   k_hist:        counts[ji[t]]++
//   k_scan_bsum:   per-256-chunk sums
//   k_scan_top:    exclusive scan of chunk sums (single block)
//   k_scan_down:   offsets[]/cursor[] = global exclusive scan of counts
//   k_scatter_pay: pos = cursor[ji[t]]++; kj_s[pos]=kj[t];
//                  sbf row (8 f32, padded) -> odd half of out row (cols 64..127)
// ---------------------------------------------------------------------------
__launch_bounds__(256)
__global__ void k_hist(const int* __restrict__ ji, int* __restrict__ counts, int T) {
    int i = blockIdx.x * 256 + threadIdx.x;
    int n = gridDim.x * 256;
    for (int t = i; t < T; t += n) atomicAdd(&counts[ji[t]], 1);
}

__launch_bounds__(256)
__global__ void k_scan_bsum(const int* __restrict__ counts, int* __restrict__ bsum) {
    __shared__ int sm[256];
    int tid = threadIdx.x;
    sm[tid] = counts[blockIdx.x * 256 + tid];
    __syncthreads();
#pragma unroll
    for (int off = 128; off > 0; off >>= 1) {
        if (tid < off) sm[tid] += sm[tid + off];
        __syncthreads();
    }
    if (tid == 0) bsum[blockIdx.x] = sm[0];
}

__launch_bounds__(1024)
__global__ void k_scan_top(int* __restrict__ bsum, int NB) {
    __shared__ int sm[1024];
    int tid = threadIdx.x;
    int v = (tid < NB) ? bsum[tid] : 0;
    sm[tid] = v;
    __syncthreads();
    for (int off = 1; off < 1024; off <<= 1) {
        int x = (tid >= off) ? sm[tid - off] : 0;
        __syncthreads();
        sm[tid] += x;
        __syncthreads();
    }
    if (tid < NB) bsum[tid] = sm[tid] - v;  // exclusive
}

__launch_bounds__(256)
__global__ void k_scan_down(const int* __restrict__ counts, const int* __restrict__ bsum,
                            int* __restrict__ offsets, int* __restrict__ cursor) {
    __shared__ int sm[256];
    int tid = threadIdx.x;
    int g = blockIdx.x * 256 + tid;
    int v = counts[g];
    sm[tid] = v;
    __syncthreads();
    for (int off = 1; off < 256; off <<= 1) {
        int x = (tid >= off) ? sm[tid - off] : 0;
        __syncthreads();
        sm[tid] += x;
        __syncthreads();
    }
    int o = bsum[blockIdx.x] + sm[tid] - v;
    offsets[g] = o;
    cursor[g]  = o;
}

__launch_bounds__(256)
__global__ void k_scatter_pay(const int* __restrict__ ji, const int* __restrict__ kj,
                              const float* __restrict__ sbf, int* __restrict__ cursor,
                              int* __restrict__ kj_s, float* __restrict__ out, int T) {
    int i = blockIdx.x * 256 + threadIdx.x;
    int n = gridDim.x * 256;
    for (int t = i; t < T; t += n) {
        int b = ji[t];
        int pos = atomicAdd(&cursor[b], 1);
        kj_s[pos] = kj[t];
        const float* sp = &sbf[(size_t)t * NSPH];
        float4 lo, hi;
        lo.x = sp[0]; lo.y = sp[1]; lo.z = sp[2]; lo.w = sp[3];
        hi.x = sp[4]; hi.y = sp[5]; hi.z = sp[6]; hi.w = 0.f;
        // sbf payload lives in the (unused-until-k3) odd half of out rows:
        // triplet pos -> out row (pos>>3), floats [64 + (pos&7)*8, +8)
        float* dst = &out[((size_t)(pos >> 3)) * 128 + 64 + (pos & 7) * 8];
        *(float4*)dst = lo;
        *(float4*)(dst + 4) = hi;
    }
}

// ---------------------------------------------------------------------------
// K2'': one wave per run of contiguous segments. For each segment, the
// triplet list [st, st+c) is contiguous: lane i loads triplet i's kj and sbf
// row in ONE masked vector load each, then 8-wide batches broadcast (readlane)
// and issue 8 independent X-row gathers -> latency chain depth ~2 per segment
// instead of ~3 per triplet. One plain store per segment, no atomics.
// ---------------------------------------------------------------------------
__launch_bounds__(256)
__global__ void k2_sorted(const int* __restrict__ kj_s, const int* __restrict__ offsets,
                          const int* __restrict__ counts, const ushort* __restrict__ X,
                          const float* __restrict__ Wsbf, const float* __restrict__ Wsbf0,
                          float* __restrict__ out, int E) {
    const int lane = threadIdx.x & 63;
    // wc[lane][k] = (W_sbf @ W_sbf0)[lane][k]
    float wj[NSPH], wc[NSPH];
#pragma unroll
    for (int i = 0; i < NSPH; i++) wj[i] = Wsbf[lane * NSPH + i];
#pragma unroll
    for (int k = 0; k < NSPH; k++) {
        float a = 0.f;
#pragma unroll
        for (int i = 0; i < NSPH; i++) a += wj[i] * Wsbf0[i * NSPH + k];
        wc[k] = a;
    }

    int gw = (blockIdx.x * 256 + threadIdx.x) >> 6;
    int nw = (gridDim.x * 256) >> 6;
    int segw = (E + nw - 1) / nw;
    int rbeg = gw * segw;
    int rend = rbeg + segw; if (rend > E) rend = E;

    for (int r = rbeg; r < rend; ++r) {
        int rs = __builtin_amdgcn_readfirstlane(r);
        int st = offsets[rs];
        int c  = counts[rs];
        float acc = 0.f;
        for (int done = 0; done < c; done += 64) {
            int cl = c - done; if (cl > 64) cl = 64;
            int j  = st + done + lane;
            int kjv = 0;
            float sb0 = 0.f, sb1 = 0.f, sb2 = 0.f, sb3 = 0.f, sb4 = 0.f, sb5 = 0.f, sb6 = 0.f;
            if (lane < cl) {
                kjv = kj_s[j];
                const float* sp = &out[((size_t)(j >> 3)) * 128 + 64 + (j & 7) * 8];
                float4 lo = *(const float4*)sp;
                float4 hi = *(const float4*)(sp + 4);
                sb0 = lo.x; sb1 = lo.y; sb2 = lo.z; sb3 = lo.w;
                sb4 = hi.x; sb5 = hi.y; sb6 = hi.z;
            }
            for (int i0 = 0; i0 < cl; i0 += 8) {
                int aa[8];
                ushort raw[8];
                // pass 1: broadcast kj and fire 8 independent X-row gathers
#pragma unroll
                for (int k8 = 0; k8 < 8; k8++) {
                    int ii = i0 + k8; if (ii > cl - 1) ii = cl - 1;  // clamp (guarded below)
                    aa[k8] = __builtin_amdgcn_readlane(kjv, ii);
                    raw[k8] = X[(size_t)aa[k8] * 64 + lane];
                }
                // pass 2: sbf dot (overlaps load latency) + accumulate
#pragma unroll
                for (int k8 = 0; k8 < 8; k8++) {
                    int ii = i0 + k8; if (ii > cl - 1) ii = cl - 1;
                    float s = wc[0] * __int_as_float(__builtin_amdgcn_readlane(__float_as_int(sb0), ii));
                    s += wc[1] * __int_as_float(__builtin_amdgcn_readlane(__float_as_int(sb1), ii));
                    s += wc[2] * __int_as_float(__builtin_amdgcn_readlane(__float_as_int(sb2), ii));
                    s += wc[3] * __int_as_float(__builtin_amdgcn_readlane(__float_as_int(sb3), ii));
                    s += wc[4] * __int_as_float(__builtin_amdgcn_readlane(__float_as_int(sb4), ii));
                    s += wc[5] * __int_as_float(__builtin_amdgcn_readlane(__float_as_int(sb5), ii));
                    s += wc[6] * __int_as_float(__builtin_amdgcn_readlane(__float_as_int(sb6), ii));
                    if (i0 + k8 >= cl) s = 0.f;   // kill clamped duplicates
                    acc += b2f(raw[k8]) * s;
                }
            }
        }
        out[(size_t)rs * 128 + lane] = acc;  // zero for empty segments
    }
}

// ---------------------------------------------------------------------------
// K3 (fused), per 128-row block:
//   GEMM1: Utile[128,128] = silu(agg_tile[128,64] @ W_up[128,64]^T) -> LDS bf16
//   GEMM2: out = silu([edge_tile | Utile] @ W_e1[128,256]^T + b) + edge_tile
// ---------------------------------------------------------------------------
__launch_bounds__(256)
__global__ void k3_fused(const float* __restrict__ edge, const float* __restrict__ Wu,
                         const float* __restrict__ We, const float* __restrict__ bias,
                         float* out) {
    __shared__ __align__(16) short Ut[128 * 136];
    const int tid  = threadIdx.x;
    const int lane = tid & 63;
    const int w    = tid >> 6;
    const int quad = lane >> 4;
    const int m16  = lane & 15;
    const int r0   = blockIdx.x * 128;
    const int rowbase = (w >> 1) * 64;
    const int colbase = (w & 1) * 64;

    // ---- GEMM1 ----
    f32x4 acc1[4][4];
#pragma unroll
    for (int mi = 0; mi < 4; mi++)
#pragma unroll
        for (int ni = 0; ni < 4; ni++) acc1[mi][ni] = (f32x4){0.f, 0.f, 0.f, 0.f};

#pragma unroll
    for (int kk = 0; kk < 64; kk += 32) {
        bf16x8 a[4], b[4];
#pragma unroll
        for (int mi = 0; mi < 4; mi++)
            a[mi] = ld8_f32_to_bf16(&out[(size_t)(r0 + rowbase + mi * 16 + m16) * 128 + kk + quad * 8]);
#pragma unroll
        for (int ni = 0; ni < 4; ni++)
            b[ni] = ld8_f32_to_bf16(&Wu[(colbase + ni * 16 + m16) * 64 + kk + quad * 8]);
#pragma unroll
        for (int mi = 0; mi < 4; mi++)
#pragma unroll
            for (int ni = 0; ni < 4; ni++)
                acc1[mi][ni] = __builtin_amdgcn_mfma_f32_16x16x32_bf16(a[mi], b[ni], acc1[mi][ni], 0, 0, 0);
    }
#pragma unroll
    for (int mi = 0; mi < 4; mi++)
#pragma unroll
        for (int ni = 0; ni < 4; ni++)
#pragma unroll
            for (int r = 0; r < 4; r++) {
                int rl = rowbase + mi * 16 + quad * 4 + r;
                int cl = colbase + ni * 16 + m16;
                Ut[rl * 136 + cl] = (short)f2b(silu_f(acc1[mi][ni][r]));
            }
    __syncthreads();

    // ---- GEMM2 ----
    f32x4 acc2[4][4];
#pragma unroll
    for (int mi = 0; mi < 4; mi++)
#pragma unroll
        for (int ni = 0; ni < 4; ni++) acc2[mi][ni] = (f32x4){0.f, 0.f, 0.f, 0.f};

#pragma unroll
    for (int k = 0; k < 256; k += 32) {
        bf16x8 a[4], b[4];
#pragma unroll
        for (int mi = 0; mi < 4; mi++) {
            int rl = rowbase + mi * 16 + m16;
            if (k < 128)
                a[mi] = ld8_f32_to_bf16(&edge[(size_t)(r0 + rl) * 128 + k + quad * 8]);
            else
                a[mi] = *(const bf16x8*)&Ut[rl * 136 + (k - 128) + quad * 8];
        }
#pragma unroll
        for (int ni = 0; ni < 4; ni++)
            b[ni] = ld8_f32_to_bf16(&We[(size_t)(colbase + ni * 16 + m16) * 256 + k + quad * 8]);
#pragma unroll
        for (int mi = 0; mi < 4; mi++)
#pragma unroll
            for (int ni = 0; ni < 4; ni++)
                acc2[mi][ni] = __builtin_amdgcn_mfma_f32_16x16x32_bf16(a[mi], b[ni], acc2[mi][ni], 0, 0, 0);
    }

#pragma unroll
    for (int mi = 0; mi < 4; mi++)
#pragma unroll
        for (int ni = 0; ni < 4; ni++) {
            int col = colbase + ni * 16 + m16;
            float bcol = bias[col];
#pragma unroll
            for (int r = 0; r < 4; r++) {
                int row = r0 + rowbase + mi * 16 + quad * 4 + r;
                float pre = acc2[mi][ni][r] + bcol;
                out[(size_t)row * 128 + col] = silu_f(pre) + edge[(size_t)row * 128 + col];
            }
        }
}

// ---------------------------------------------------------------------------
extern "C" void kernel_launch(void* const* d_in, const int* in_sizes, int n_in,
                              void* d_out, int out_size, void* d_ws, size_t ws_size,
                              hipStream_t stream) {
    const float* edge  = (const float*)d_in[0];
    const float* sbf   = (const float*)d_in[1];
    const int*   idxkj = (const int*)d_in[2];
    const int*   idxji = (const int*)d_in[3];
    const float* Wsbf0 = (const float*)d_in[4];
    const float* Wsbf  = (const float*)d_in[5];
    const float* We1   = (const float*)d_in[6];
    const float* be1   = (const float*)d_in[7];
    const float* Wdown = (const float*)d_in[8];
    const float* Wup   = (const float*)d_in[9];

    const int E = in_sizes[0] / 128;
    const int T = in_sizes[2];
    const int NB = E / 256;  // 1024 for E=262144

    // workspace layout: X | counts | offsets | cursor | kj_s | bsum (~45 MB)
    ushort* X       = (ushort*)d_ws;                                  // E*64 bf16
    int*    counts  = (int*)((char*)d_ws + (size_t)E * 64 * 2);       // E
    int*    offsets = counts + E;                                     // E
    int*    cursor  = offsets + E;                                    // E
    int*    kj_s    = cursor + E;                                     // T
    int*    bsum    = kj_s + T;                                       // NB (<=1024)

    float* out = (float*)d_out;  // E*128 f32; agg in cols 0..63, sbf payload staged in cols 64..127

    hipMemsetAsync(counts, 0, (size_t)E * sizeof(int), stream);

    k1_down<<<E / 128, 256, 0, stream>>>(edge, Wdown, X);

    // counting sort of triplets by ji (payload carried: kj + sbf row)
    k_hist<<<2048, 256, 0, stream>>>(idxji, counts, T);
    k_scan_bsum<<<NB, 256, 0, stream>>>(counts, bsum);
    k_scan_top<<<1, 1024, 0, stream>>>(bsum, NB);
    k_scan_down<<<NB, 256, 0, stream>>>(counts, bsum, offsets, cursor);
    k_scatter_pay<<<2048, 256, 0, stream>>>(idxji, idxkj, sbf, cursor, kj_s, out, T);

    // ownership-based segment reduction (no atomics, batched gathers)
    k2_sorted<<<4096, 256, 0, stream>>>(kj_s, offsets, counts, X, Wsbf, Wsbf0, out, E);

    k3_fused<<<E / 128, 256, 0, stream>>>(edge, Wup, We1, be1, out);
}

// Round 3
// 805.114 us; speedup vs baseline: 1.3784x; 1.0859x over previous
//
#include <hip/hip_runtime.h>
#include <hip/hip_bf16.h>

#define NSPH 7

typedef short bf16x8 __attribute__((ext_vector_type(8)));
typedef float f32x4 __attribute__((ext_vector_type(4)));

static __device__ __forceinline__ ushort f2b(float f) {
    union { __hip_bfloat16 h; ushort u; } v; v.h = __float2bfloat16(f); return v.u;
}
static __device__ __forceinline__ float b2f(ushort u) {
    union { unsigned int i; float f; } v; v.i = ((unsigned int)u) << 16; return v.f;
}
static __device__ __forceinline__ float silu_f(float v) {
    return v / (1.0f + __expf(-v));
}
// load 8 consecutive f32 from p, round to bf16x8
static __device__ __forceinline__ bf16x8 ld8_f32_to_bf16(const float* p) {
    float4 p0 = *(const float4*)p;
    float4 p1 = *(const float4*)(p + 4);
    bf16x8 r;
    r[0] = (short)f2b(p0.x); r[1] = (short)f2b(p0.y);
    r[2] = (short)f2b(p0.z); r[3] = (short)f2b(p0.w);
    r[4] = (short)f2b(p1.x); r[5] = (short)f2b(p1.y);
    r[6] = (short)f2b(p1.z); r[7] = (short)f2b(p1.w);
    return r;
}

// ---------------------------------------------------------------------------
// K1: X[E,64] = silu(edge[E,128] @ W_down[64,128]^T), X stored bf16.
// ALSO stores the bf16-rounded edge tile (already computed for the MFMA
// A-frags) into out rows bytes 0..255 (f32 cols 0..63) as "edgeb" for k3.
// ---------------------------------------------------------------------------
__launch_bounds__(256)
__global__ void k1_down(const float* __restrict__ edge, const float* __restrict__ Wd,
                        ushort* __restrict__ X, ushort* __restrict__ outb) {
    const int tid  = threadIdx.x;
    const int lane = tid & 63;
    const int w    = tid >> 6;
    const int quad = lane >> 4;
    const int m16  = lane & 15;
    const int r0   = blockIdx.x * 128 + w * 32;

    f32x4 acc[2][4];
#pragma unroll
    for (int mi = 0; mi < 2; mi++)
#pragma unroll
        for (int ni = 0; ni < 4; ni++) acc[mi][ni] = (f32x4){0.f, 0.f, 0.f, 0.f};

#pragma unroll
    for (int k = 0; k < 128; k += 32) {
        bf16x8 a[2], b[4];
#pragma unroll
        for (int mi = 0; mi < 2; mi++) {
            int row = r0 + mi * 16 + m16;
            a[mi] = ld8_f32_to_bf16(&edge[(size_t)row * 128 + k + quad * 8]);
            // edgeb store: out row bytes 0..255 hold bf16(edge[row, 0..127])
            *(bf16x8*)&outb[(size_t)row * 256 + k + quad * 8] = a[mi];
        }
#pragma unroll
        for (int ni = 0; ni < 4; ni++)
            b[ni] = ld8_f32_to_bf16(&Wd[(ni * 16 + m16) * 128 + k + quad * 8]);
#pragma unroll
        for (int mi = 0; mi < 2; mi++)
#pragma unroll
            for (int ni = 0; ni < 4; ni++)
                acc[mi][ni] = __builtin_amdgcn_mfma_f32_16x16x32_bf16(a[mi], b[ni], acc[mi][ni], 0, 0, 0);
    }
#pragma unroll
    for (int mi = 0; mi < 2; mi++)
#pragma unroll
        for (int ni = 0; ni < 4; ni++)
#pragma unroll
            for (int r = 0; r < 4; r++) {
                int row = r0 + mi * 16 + quad * 4 + r;
                int col = ni * 16 + m16;
                X[(size_t)row * 64 + col] = f2b(silu_f(acc[mi][ni][r]));
            }
}

// ---------------------------------------------------------------------------
// Tiny one-shot weight conversion: Web = bf16(W_e1[128,256]), Wub = bf16(W_up[128,64])
// ---------------------------------------------------------------------------
__launch_bounds__(256)
__global__ void k_cvt_w(const float* __restrict__ We, const float* __restrict__ Wu,
                        ushort* __restrict__ Web, ushort* __restrict__ Wub) {
    int i = blockIdx.x * 256 + threadIdx.x;
    if (i < 128 * 256) Web[i] = f2b(We[i]);
    if (i < 128 * 64)  Wub[i] = f2b(Wu[i]);
}

// ---------------------------------------------------------------------------
// Counting-sort of triplets by idx_ji (payload sort):
// ---------------------------------------------------------------------------
__launch_bounds__(256)
__global__ void k_hist(const int* __restrict__ ji, int* __restrict__ counts, int T) {
    int i = blockIdx.x * 256 + threadIdx.x;
    int n = gridDim.x * 256;
    for (int t = i; t < T; t += n) atomicAdd(&counts[ji[t]], 1);
}

__launch_bounds__(256)
__global__ void k_scan_bsum(const int* __restrict__ counts, int* __restrict__ bsum) {
    __shared__ int sm[256];
    int tid = threadIdx.x;
    sm[tid] = counts[blockIdx.x * 256 + tid];
    __syncthreads();
#pragma unroll
    for (int off = 128; off > 0; off >>= 1) {
        if (tid < off) sm[tid] += sm[tid + off];
        __syncthreads();
    }
    if (tid == 0) bsum[blockIdx.x] = sm[0];
}

__launch_bounds__(1024)
__global__ void k_scan_top(int* __restrict__ bsum, int NB) {
    __shared__ int sm[1024];
    int tid = threadIdx.x;
    int v = (tid < NB) ? bsum[tid] : 0;
    sm[tid] = v;
    __syncthreads();
    for (int off = 1; off < 1024; off <<= 1) {
        int x = (tid >= off) ? sm[tid - off] : 0;
        __syncthreads();
        sm[tid] += x;
        __syncthreads();
    }
    if (tid < NB) bsum[tid] = sm[tid] - v;  // exclusive
}

__launch_bounds__(256)
__global__ void k_scan_down(const int* __restrict__ counts, const int* __restrict__ bsum,
                            int* __restrict__ offsets, int* __restrict__ cursor) {
    __shared__ int sm[256];
    int tid = threadIdx.x;
    int g = blockIdx.x * 256 + tid;
    int v = counts[g];
    sm[tid] = v;
    __syncthreads();
    for (int off = 1; off < 256; off <<= 1) {
        int x = (tid >= off) ? sm[tid - off] : 0;
        __syncthreads();
        sm[tid] += x;
        __syncthreads();
    }
    int o = bsum[blockIdx.x] + sm[tid] - v;
    offsets[g] = o;
    cursor[g]  = o;
}

__launch_bounds__(256)
__global__ void k_scatter_pay(const int* __restrict__ ji, const int* __restrict__ kj,
                              const float* __restrict__ sbf, int* __restrict__ cursor,
                              int* __restrict__ kj_s, float* __restrict__ out, int T) {
    int i = blockIdx.x * 256 + threadIdx.x;
    int n = gridDim.x * 256;
    for (int t = i; t < T; t += n) {
        int b = ji[t];
        int pos = atomicAdd(&cursor[b], 1);
        kj_s[pos] = kj[t];
        const float* sp = &sbf[(size_t)t * NSPH];
        float4 lo, hi;
        lo.x = sp[0]; lo.y = sp[1]; lo.z = sp[2]; lo.w = sp[3];
        hi.x = sp[4]; hi.y = sp[5]; hi.z = sp[6]; hi.w = 0.f;
        // sbf payload lives in the odd half of out rows (f32 cols 64..127):
        // triplet pos -> out row (pos>>3), floats [64 + (pos&7)*8, +8)
        float* dst = &out[((size_t)(pos >> 3)) * 128 + 64 + (pos & 7) * 8];
        *(float4*)dst = lo;
        *(float4*)(dst + 4) = hi;
    }
}

// ---------------------------------------------------------------------------
// K2: one wave per run of contiguous segments; batched gathers; writes agg
// directly as bf16 to aggb[E,64] (identical rounding to the old f32->bf16
// path in k3's GEMM1). No atomics.
// ---------------------------------------------------------------------------
__launch_bounds__(256)
__global__ void k2_sorted(const int* __restrict__ kj_s, const int* __restrict__ offsets,
                          const int* __restrict__ counts, const ushort* __restrict__ X,
                          const float* __restrict__ Wsbf, const float* __restrict__ Wsbf0,
                          const float* __restrict__ out, ushort* __restrict__ aggb, int E) {
    const int lane = threadIdx.x & 63;
    float wj[NSPH], wc[NSPH];
#pragma unroll
    for (int i = 0; i < NSPH; i++) wj[i] = Wsbf[lane * NSPH + i];
#pragma unroll
    for (int k = 0; k < NSPH; k++) {
        float a = 0.f;
#pragma unroll
        for (int i = 0; i < NSPH; i++) a += wj[i] * Wsbf0[i * NSPH + k];
        wc[k] = a;
    }

    int gw = (blockIdx.x * 256 + threadIdx.x) >> 6;
    int nw = (gridDim.x * 256) >> 6;
    int segw = (E + nw - 1) / nw;
    int rbeg = gw * segw;
    int rend = rbeg + segw; if (rend > E) rend = E;

    for (int r = rbeg; r < rend; ++r) {
        int rs = __builtin_amdgcn_readfirstlane(r);
        int st = offsets[rs];
        int c  = counts[rs];
        float acc = 0.f;
        for (int done = 0; done < c; done += 64) {
            int cl = c - done; if (cl > 64) cl = 64;
            int j  = st + done + lane;
            int kjv = 0;
            float sb0 = 0.f, sb1 = 0.f, sb2 = 0.f, sb3 = 0.f, sb4 = 0.f, sb5 = 0.f, sb6 = 0.f;
            if (lane < cl) {
                kjv = kj_s[j];
                const float* sp = &out[((size_t)(j >> 3)) * 128 + 64 + (j & 7) * 8];
                float4 lo = *(const float4*)sp;
                float4 hi = *(const float4*)(sp + 4);
                sb0 = lo.x; sb1 = lo.y; sb2 = lo.z; sb3 = lo.w;
                sb4 = hi.x; sb5 = hi.y; sb6 = hi.z;
            }
            for (int i0 = 0; i0 < cl; i0 += 8) {
                int aa[8];
                ushort raw[8];
#pragma unroll
                for (int k8 = 0; k8 < 8; k8++) {
                    int ii = i0 + k8; if (ii > cl - 1) ii = cl - 1;
                    aa[k8] = __builtin_amdgcn_readlane(kjv, ii);
                    raw[k8] = X[(size_t)aa[k8] * 64 + lane];
                }
#pragma unroll
                for (int k8 = 0; k8 < 8; k8++) {
                    int ii = i0 + k8; if (ii > cl - 1) ii = cl - 1;
                    float s = wc[0] * __int_as_float(__builtin_amdgcn_readlane(__float_as_int(sb0), ii));
                    s += wc[1] * __int_as_float(__builtin_amdgcn_readlane(__float_as_int(sb1), ii));
                    s += wc[2] * __int_as_float(__builtin_amdgcn_readlane(__float_as_int(sb2), ii));
                    s += wc[3] * __int_as_float(__builtin_amdgcn_readlane(__float_as_int(sb3), ii));
                    s += wc[4] * __int_as_float(__builtin_amdgcn_readlane(__float_as_int(sb4), ii));
                    s += wc[5] * __int_as_float(__builtin_amdgcn_readlane(__float_as_int(sb5), ii));
                    s += wc[6] * __int_as_float(__builtin_amdgcn_readlane(__float_as_int(sb6), ii));
                    if (i0 + k8 >= cl) s = 0.f;
                    acc += b2f(raw[k8]) * s;
                }
            }
        }
        aggb[(size_t)rs * 64 + lane] = f2b(acc);  // zero for empty segments
    }
}

// ---------------------------------------------------------------------------
// K3 v2: 512 threads, 8 waves, each owns a 32x64 sub-tile (acc = 32 AGPRs).
// All MFMA operands pre-converted bf16: aggb (ws), edgeb (out bytes 0..255),
// Wub/Web (ws). Barrier before epilogue protects edgeb-in-out from overwrite.
//   GEMM1: U[128,128] = silu(agg[128,64] @ Wup^T) -> LDS bf16
//   GEMM2: out = silu([edgeb | U] @ We^T + b) + edge(f32)
// ---------------------------------------------------------------------------
__launch_bounds__(512)
__global__ void k3_fused(const float* __restrict__ edge, const ushort* __restrict__ aggb,
                         const ushort* __restrict__ Wub, const ushort* __restrict__ Web,
                         const float* __restrict__ bias, float* __restrict__ out) {
    __shared__ __align__(16) ushort Ut[128 * 136];
    const int tid  = threadIdx.x;
    const int lane = tid & 63;
    const int w    = tid >> 6;      // 0..7
    const int quad = lane >> 4;
    const int m16  = lane & 15;
    const int wr   = w >> 1;        // 0..3 -> 32-row group
    const int wc   = w & 1;         // 0..1 -> 64-col group
    const int r0   = blockIdx.x * 128;
    const int rowbase = wr * 32;
    const int colbase = wc * 64;
    ushort* outb = (ushort*)out;    // bf16 view: row stride 256 ushorts

    // ---- GEMM1 ----
    f32x4 acc[2][4];
#pragma unroll
    for (int mi = 0; mi < 2; mi++)
#pragma unroll
        for (int ni = 0; ni < 4; ni++) acc[mi][ni] = (f32x4){0.f, 0.f, 0.f, 0.f};

#pragma unroll
    for (int kk = 0; kk < 64; kk += 32) {
        bf16x8 a[2], b[4];
#pragma unroll
        for (int mi = 0; mi < 2; mi++)
            a[mi] = *(const bf16x8*)&aggb[(size_t)(r0 + rowbase + mi * 16 + m16) * 64 + kk + quad * 8];
#pragma unroll
        for (int ni = 0; ni < 4; ni++)
            b[ni] = *(const bf16x8*)&Wub[(colbase + ni * 16 + m16) * 64 + kk + quad * 8];
#pragma unroll
        for (int mi = 0; mi < 2; mi++)
#pragma unroll
            for (int ni = 0; ni < 4; ni++)
                acc[mi][ni] = __builtin_amdgcn_mfma_f32_16x16x32_bf16(a[mi], b[ni], acc[mi][ni], 0, 0, 0);
    }
#pragma unroll
    for (int mi = 0; mi < 2; mi++)
#pragma unroll
        for (int ni = 0; ni < 4; ni++)
#pragma unroll
            for (int r = 0; r < 4; r++) {
                int rl = rowbase + mi * 16 + quad * 4 + r;
                int cl = colbase + ni * 16 + m16;
                Ut[rl * 136 + cl] = f2b(silu_f(acc[mi][ni][r]));
            }
    __syncthreads();

    // ---- GEMM2 ----
#pragma unroll
    for (int mi = 0; mi < 2; mi++)
#pragma unroll
        for (int ni = 0; ni < 4; ni++) acc[mi][ni] = (f32x4){0.f, 0.f, 0.f, 0.f};

#pragma unroll
    for (int k = 0; k < 256; k += 32) {
        bf16x8 a[2], b[4];
#pragma unroll
        for (int mi = 0; mi < 2; mi++) {
            int rl = rowbase + mi * 16 + m16;
            if (k < 128)
                a[mi] = *(const bf16x8*)&outb[(size_t)(r0 + rl) * 256 + k + quad * 8];
            else
                a[mi] = *(const bf16x8*)&Ut[rl * 136 + (k - 128) + quad * 8];
        }
#pragma unroll
        for (int ni = 0; ni < 4; ni++)
            b[ni] = *(const bf16x8*)&Web[(size_t)(colbase + ni * 16 + m16) * 256 + k + quad * 8];
#pragma unroll
        for (int mi = 0; mi < 2; mi++)
#pragma unroll
            for (int ni = 0; ni < 4; ni++)
                acc[mi][ni] = __builtin_amdgcn_mfma_f32_16x16x32_bf16(a[mi], b[ni], acc[mi][ni], 0, 0, 0);
    }

    // all edgeb reads done before any wave overwrites out
    __syncthreads();

#pragma unroll
    for (int mi = 0; mi < 2; mi++)
#pragma unroll
        for (int ni = 0; ni < 4; ni++) {
            int col = colbase + ni * 16 + m16;
            float bcol = bias[col];
#pragma unroll
            for (int r = 0; r < 4; r++) {
                int row = r0 + rowbase + mi * 16 + quad * 4 + r;
                float pre = acc[mi][ni][r] + bcol;
                out[(size_t)row * 128 + col] = silu_f(pre) + edge[(size_t)row * 128 + col];
            }
        }
}

// ---------------------------------------------------------------------------
extern "C" void kernel_launch(void* const* d_in, const int* in_sizes, int n_in,
                              void* d_out, int out_size, void* d_ws, size_t ws_size,
                              hipStream_t stream) {
    const float* edge  = (const float*)d_in[0];
    const float* sbf   = (const float*)d_in[1];
    const int*   idxkj = (const int*)d_in[2];
    const int*   idxji = (const int*)d_in[3];
    const float* Wsbf0 = (const float*)d_in[4];
    const float* Wsbf  = (const float*)d_in[5];
    const float* We1   = (const float*)d_in[6];
    const float* be1   = (const float*)d_in[7];
    const float* Wdown = (const float*)d_in[8];
    const float* Wup   = (const float*)d_in[9];

    const int E = in_sizes[0] / 128;
    const int T = in_sizes[2];
    const int NB = E / 256;  // 1024 for E=262144

    // workspace layout (~79 MB):
    // X | aggb | counts | offsets | cursor | kj_s | bsum | Web | Wub
    ushort* X       = (ushort*)d_ws;                                  // E*64 bf16
    ushort* aggb    = X + (size_t)E * 64;                             // E*64 bf16
    int*    counts  = (int*)(aggb + (size_t)E * 64);                  // E
    int*    offsets = counts + E;                                     // E
    int*    cursor  = offsets + E;                                    // E
    int*    kj_s    = cursor + E;                                     // T
    int*    bsum    = kj_s + T;                                       // NB (<=1024)
    ushort* Web     = (ushort*)(bsum + 1024);                         // 128*256
    ushort* Wub     = Web + 128 * 256;                                // 128*64

    float* out = (float*)d_out;  // edgeb in cols 0..63 (bytes), sbf payload in cols 64..127

    hipMemsetAsync(counts, 0, (size_t)E * sizeof(int), stream);

    k_cvt_w<<<128, 256, 0, stream>>>(We1, Wup, Web, Wub);
    k1_down<<<E / 128, 256, 0, stream>>>(edge, Wdown, X, (ushort*)out);

    // counting sort of triplets by ji (payload carried: kj + sbf row)
    k_hist<<<2048, 256, 0, stream>>>(idxji, counts, T);
    k_scan_bsum<<<NB, 256, 0, stream>>>(counts, bsum);
    k_scan_top<<<1, 1024, 0, stream>>>(bsum, NB);
    k_scan_down<<<NB, 256, 0, stream>>>(counts, bsum, offsets, cursor);
    k_scatter_pay<<<2048, 256, 0, stream>>>(idxji, idxkj, sbf, cursor, kj_s, out, T);

    // ownership-based segment reduction -> bf16 agg
    k2_sorted<<<4096, 256, 0, stream>>>(kj_s, offsets, counts, X, Wsbf, Wsbf0,
                                        out, aggb, E);

    k3_fused<<<E / 128, 512, 0, stream>>>(edge, aggb, Wub, Web, be1, out);
}